// Round 1
// baseline (174.356 us; speedup 1.0000x reference)
//
#include <hip/hip_runtime.h>

// Chunked fast-weight linear attention, MI355X gfx950.
// grid = 32 bh * 8 vgroups = 256 wgs (1/CU), 512 threads (8 waves).
// Per chunk: stage q,k,vT (fp32->f16 LDS, XOR-swizzled) -> A = mask(q k^T)
// -> out = A@v + q@W_prev -> W += k^T v (state in regs + f16 LDS, dbuf).

typedef _Float16 f16;
typedef __attribute__((ext_vector_type(4))) _Float16 f16x4;
typedef __attribute__((ext_vector_type(8))) _Float16 f16x8;
typedef __attribute__((ext_vector_type(4))) float f32x4;
typedef __attribute__((ext_vector_type(4))) float fv4;

#define MFMA16(a, b, c) __builtin_amdgcn_mfma_f32_16x16x32_f16((a), (b), (c), 0, 0, 0)

// Byte offset into a row-major [*][128] f16 LDS tile, XOR-16B swizzle
// (breaks the stride-256B bank collision on fragment reads; G4 pattern).
__device__ __forceinline__ int swzb(int row, int col) {
  return ((row << 8) + (col << 1)) ^ ((row & 7) << 4);
}

// 8-f16 MFMA operand fragment. Our k-map: k = 8*(lane>>4) + j, applied to
// BOTH A and B operands of every MFMA -> any bijective per-(group,reg) k-map
// yields the correct contraction (HW pairs equal (group,reg) slots).
// One ds_read_b128 per fragment.
__device__ __forceinline__ f16x8 fragr(const f16* lds, int row, int kbase, int lane) {
  int c0 = kbase + ((lane >> 4) << 3);
  return *(const f16x8*)((const char*)lds + swzb(row, c0));
}

// Transposed fragment (B operand of the state update): element j comes from
// k_lds[kbase + 8*(lane>>4) + j][col]. 8 scalar reads; small fraction of work.
__device__ __forceinline__ f16x8 fragkT(const f16* lds, int kbase, int col, int lane) {
  f16x8 r;
  int r0 = kbase + ((lane >> 4) << 3);
#pragma unroll
  for (int j = 0; j < 8; ++j)
    r[j] = *(const f16*)((const char*)lds + swzb(r0 + j, col));
  return r;
}

__global__ __launch_bounds__(512, 1)
void ttr_fastweight(const float* __restrict__ q, const float* __restrict__ k,
                    const float* __restrict__ v, float* __restrict__ out) {
  __shared__ f16 q_lds[128 * 128];      // 32 KB
  __shared__ f16 k_lds[128 * 128];      // 32 KB
  __shared__ f16 a_lds[128 * 128];      // 32 KB (masked scores, f16)
  __shared__ f16 vT_lds[16 * 128];      // 4 KB  (v slice, transposed)
  __shared__ f16 wT_lds[2][16 * 128];   // 8 KB  (state W^T, double-buffered)

  const int tid = threadIdx.x;
  const int lane = tid & 63;
  const int wave = tid >> 6;
  const int vg = blockIdx.x >> 5;   // 0..7  (v-column group of 16)
  const int b = blockIdx.x & 31;    // 0..31 (batch-head); same b -> same XCD

  const float* qb = q + (size_t)b * (4096 * 128);
  const float* kb = k + (size_t)b * (4096 * 128);
  const float* vb = v + (size_t)b * (4096 * 128) + vg * 16;
  float* ob = out + (size_t)b * (4096 * 128) + vg * 16;

  for (int i = tid; i < 16 * 128; i += 512) wT_lds[0][i] = (f16)0.f;

  f32x4 wacc = {0.f, 0.f, 0.f, 0.f};  // running W^T tile: [16v] x [16f of wave]
  __syncthreads();

  const int colj = lane & 15;          // MFMA n/col (and A-operand row) index
  const int row4 = (lane >> 4) << 2;   // MFMA C/D row base: row = row4 + reg

  for (int chunk = 0; chunk < 32; ++chunk) {
    const int cur = chunk & 1, nxt = cur ^ 1;
    __syncthreads();  // B1: all reads of q/k/vT/a_lds from prev chunk done

    // ---------------- stage q,k (f32 -> f16, swizzled) ----------------
    {
      const float* qg = qb + (size_t)chunk * (128 * 128);
      const float* kg = kb + (size_t)chunk * (128 * 128);
      int rr = tid >> 5;             // 0..15
      int cc = (tid & 31) << 2;      // 0..124
#pragma unroll
      for (int p = 0; p < 8; ++p) {
        int row = (p << 4) + rr;
        fv4 x = *(const fv4*)(qg + row * 128 + cc);
        f16x4 h = {(f16)x[0], (f16)x[1], (f16)x[2], (f16)x[3]};
        *(f16x4*)((char*)q_lds + swzb(row, cc)) = h;
        fv4 y = *(const fv4*)(kg + row * 128 + cc);
        f16x4 h2 = {(f16)y[0], (f16)y[1], (f16)y[2], (f16)y[3]};
        *(f16x4*)((char*)k_lds + swzb(row, cc)) = h2;
      }
      // v slice -> vT_lds[16][128]
      const float* vgp = vb + (size_t)chunk * (128 * 128);
      int vrow = tid >> 2;           // 0..127
      int vp = (tid & 3) << 2;       // 0,4,8,12
      fv4 xv = *(const fv4*)(vgp + vrow * 128 + vp);
#pragma unroll
      for (int t = 0; t < 4; ++t)
        *(f16*)((char*)vT_lds + swzb(vp + t, vrow)) = (f16)xv[t];
    }
    __syncthreads();  // B2: staged data visible

    // ------- phase 1: A tiles (causal) + state update (this chunk) -------
    {
      int u = 0;
      for (int r = 0; r < 8; ++r) {
        for (int c = 0; c <= r; ++c) {
          if ((u++ & 7) != wave) continue;   // 36 tiles round-robin over 8 waves
          f32x4 acc = {0.f, 0.f, 0.f, 0.f};
          int arow = (r << 4) + colj;
          int brow = (c << 4) + colj;
#pragma unroll
          for (int kk = 0; kk < 4; ++kk)
            acc = MFMA16(fragr(q_lds, arow, kk << 5, lane),
                         fragr(k_lds, brow, kk << 5, lane), acc);
#pragma unroll
          for (int t = 0; t < 4; ++t) {
            float val = acc[t];
            if (r == c && colj > row4 + t) val = 0.f;  // inclusive causal mask
            *(f16*)((char*)a_lds + swzb((r << 4) + row4 + t, (c << 4) + colj)) =
                (f16)val;
          }
        }
      }
      // zero the half-K garbage tile (r even uses K past the diagonal)
      if (wave < 4) {
        int r = wave << 1;
#pragma unroll
        for (int t = 0; t < 4; ++t)
          *(f16*)((char*)a_lds +
                  swzb((r << 4) + row4 + t, ((r + 1) << 4) + colj)) = (f16)0.f;
      }
      // state update: W^T[v][f] += sum_j vT[v][j] * k[j][f]; wave owns f-tile
#pragma unroll
      for (int kk = 0; kk < 4; ++kk)
        wacc = MFMA16(fragr(vT_lds, colj, kk << 5, lane),
                      fragkT(k_lds, kk << 5, (wave << 4) + colj, lane), wacc);
#pragma unroll
      for (int t = 0; t < 4; ++t)
        *(f16*)((char*)wT_lds[nxt] + swzb(row4 + t, (wave << 4) + colj)) =
            (f16)wacc[t];
    }
    __syncthreads();  // B3: a_lds visible

    // ------------- phase 2: out = A@v + q@W_prev, scale, store -------------
    {
      int r = wave;
      int qrow = (r << 4) + colj;
      f32x4 acc = {0.f, 0.f, 0.f, 0.f};
#pragma unroll
      for (int kk = 0; kk < 4; ++kk)  // inter-chunk: q @ W_prev (W^T as B)
        acc = MFMA16(fragr(q_lds, qrow, kk << 5, lane),
                     fragr(wT_lds[cur], colj, kk << 5, lane), acc);
      int nkk = (r + 2) >> 1;         // ceil((r+1)/2) K-steps of 32
      for (int kk = 0; kk < nkk; ++kk)  // intra-chunk: A @ v
        acc = MFMA16(fragr(a_lds, qrow, kk << 5, lane),
                     fragr(vT_lds, colj, kk << 5, lane), acc);
      float* og = ob + (size_t)((chunk << 7) + (r << 4)) * 128 + colj;
#pragma unroll
      for (int t = 0; t < 4; ++t) {
        int lr = row4 + t;
        float tg = (float)((chunk << 7) + (r << 4) + lr + 1);
        og[(size_t)lr * 128] = acc[t] / tg;
      }
    }
  }
}

extern "C" void kernel_launch(void* const* d_in, const int* in_sizes, int n_in,
                              void* d_out, int out_size, void* d_ws, size_t ws_size,
                              hipStream_t stream) {
  const float* q = (const float*)d_in[0];
  const float* k = (const float*)d_in[1];
  const float* v = (const float*)d_in[2];
  float* o = (float*)d_out;
  // chunk_size (d_in[3]) is fixed at 128 for this problem shape.
  ttr_fastweight<<<dim3(256), dim3(512), 0, stream>>>(q, k, v, o);
}